// Round 16
// baseline (72.516 us; speedup 1.0000x reference)
//
#include <hip/hip_runtime.h>

// sample_pdf (NeRF, det=True) — rank-scan gather, all-DPP lane ops, scalar
// addressing. r15 body verbatim; ONLY change: RPW 3 -> 4 at 128-thread blocks.
// LDS 12.3 KB/block -> 13 blocks/CU = 26 waves/CU (81%), rays-in-flight/CU
// 72 -> ~104. (r7's RPW=4 failure was 256-thr blocks: 24 KB LDS -> 61% occ.)
//
// u_j=(2j+1)/256 fixed grid; g(c)=ceil(128c-0.5)=#{j:u_j<c} (exact in fp32).
// Interval k=[cdf[k],cdf[k+1]) owns sample slots [g_k,g_{k+1});
// K(j)=max{k: g_k<=j} == searchsorted(cdf,u_j,right)-1. Per ray:
// atomicMax-paint interval index k at start slot (only if g<NS), store params
// (A,B) with sample = A + u*B, wave max-scan forward-fills K(j), gather+fma.
//
// Lane 63: w0=w1=0 -> c0=c1=total*rcp(total) > 127.5/128 -> g=128 -> no paint.
//
// Cross-lane ops are DPP (pure VALU, HW-validated rounds 7-15):
//   scan: row_shr:1/2/4/8 + row_bcast:15 (rows 1,3) + row_bcast:31 (rows 2,3)
//   shfl_down(1)=wave_shl:1 (0x130); shfl_up(1)=wave_shr:1 (0x138, lane0->0)

#define M     126
#define NBINS 127
#define NS    128
#define RPW   4     // rays per wave
#define WPB   2     // waves per block (128 threads)

template<int CTRL, int RM>
__device__ __forceinline__ float dpp_f(float x) {
    return __builtin_bit_cast(float,
        __builtin_amdgcn_update_dpp(0, __builtin_bit_cast(int, x),
                                    CTRL, RM, 0xf, true));
}
template<int CTRL, int RM>
__device__ __forceinline__ int dpp_i(int x) {
    return __builtin_amdgcn_update_dpp(0, x, CTRL, RM, 0xf, true);
}

__device__ __forceinline__ float wave_iscan_add(float x) {
    x += dpp_f<0x111, 0xf>(x);   // row_shr:1
    x += dpp_f<0x112, 0xf>(x);   // row_shr:2
    x += dpp_f<0x114, 0xf>(x);   // row_shr:4
    x += dpp_f<0x118, 0xf>(x);   // row_shr:8
    x += dpp_f<0x142, 0xa>(x);   // row_bcast:15 -> rows 1,3
    x += dpp_f<0x143, 0xc>(x);   // row_bcast:31 -> rows 2,3
    return x;
}
__device__ __forceinline__ int wave_iscan_max(int x) {
    x = max(x, dpp_i<0x111, 0xf>(x));
    x = max(x, dpp_i<0x112, 0xf>(x));
    x = max(x, dpp_i<0x114, 0xf>(x));
    x = max(x, dpp_i<0x118, 0xf>(x));
    x = max(x, dpp_i<0x142, 0xa>(x));
    x = max(x, dpp_i<0x143, 0xc>(x));
    return x;
}

__global__ __launch_bounds__(64 * WPB) void sample_pdf_rank16(
    const float* __restrict__ bins,
    const float* __restrict__ weights,
    float* __restrict__ out,
    int n_rays)
{
    __shared__ int    s_idx[WPB * RPW][NS];
    __shared__ float4 s_P[WPB * RPW][NS / 2];  // (A_even, B_even, A_odd, B_odd)

    const int wave = threadIdx.x >> 6;
    const int lane = threadIdx.x & 63;
    const int base = (blockIdx.x * WPB + wave) * RPW;

    const int  i0   = min(2 * lane, 126);      // branchless, OOB-safe
    const int  i1   = min(2 * lane + 1, 126);
    const int  iw   = min(2 * lane, 124);
    const bool full = (lane < 63);

    // ---- init paint slots ----
    #pragma unroll
    for (int r = 0; r < RPW; ++r)
        *reinterpret_cast<int2*>(&s_idx[wave * RPW + r][2 * lane]) = make_int2(0, 0);

    // ---- phase A: all global loads up front (scalar row bases) ----
    bool  valid[RPW];
    float b_a[RPW], b_b[RPW];
    float2 ww[RPW];
    #pragma unroll
    for (int r = 0; r < RPW; ++r) {
        const int ry = base + r;
        valid[r] = (ry < n_rays);
        const int ryu = __builtin_amdgcn_readfirstlane(valid[r] ? ry : n_rays - 1);
        const float* brow = bins    + (size_t)ryu * NBINS;   // SGPR base
        const float* wrow = weights + (size_t)ryu * M;
        b_a[r] = brow[i0];
        b_b[r] = brow[i1];
        ww[r]  = *reinterpret_cast<const float2*>(wrow + iw);
    }
    __builtin_amdgcn_wave_barrier();

    const float u0 = fmaf((float)lane, 0.015625f, 0.00390625f); // (4l+1)/256
    const float u1 = u0 + 0.0078125f;                           // (4l+3)/256

    // ---- phase B: scan -> cdf -> ranks -> params -> paint ----
    #pragma unroll
    for (int r = 0; r < RPW; ++r) {
        const float w0  = full ? ww[r].x + 1e-5f : 0.0f;   // lane63: exactly 0
        const float w1  = full ? ww[r].y + 1e-5f : 0.0f;
        const float rw0 = __builtin_amdgcn_rcpf(w0);       // off-chain
        const float rw1 = __builtin_amdgcn_rcpf(w1);
        const float b_c = dpp_f<0x130, 0xf>(b_a[r]);       // bins[2i+2]

        const float pair  = w0 + w1;
        const float ps    = wave_iscan_add(pair);          // inclusive prefix
        const float total = __shfl(ps, 63, 64);            // v_readlane
        const float inv   = __builtin_amdgcn_rcpf(total);
        const float excl  = ps - pair;
        const float c0 = excl * inv;                       // cdf[2i]
        const float c1 = (excl + w0) * inv;                // cdf[2i+1]
        const float c2 = ps * inv;                         // cdf[2i+2]

        const int g0 = (int)ceilf(fmaf(c0, 128.0f, -0.5f));  // exact rank
        const int g1 = (int)ceilf(fmaf(c1, 128.0f, -0.5f));

        const float dA = c1 - c0;
        const float dB = c2 - c1;
        const float fA = (dA < 1e-5f) ? 1.0f : total * rw0;
        const float fB = (dB < 1e-5f) ? 1.0f : total * rw1;
        const float slA = (b_b[r] - b_a[r]) * fA;
        const float slB = (b_c    - b_b[r]) * fB;
        const float A0  = fmaf(-c0, slA, b_a[r]);          // bl - cl*sl
        const float A1  = fmaf(-c1, slB, b_b[r]);

        const int seg = wave * RPW + r;
        s_P[seg][lane] = make_float4(A0, slA, A1, slB);    // one ds_write_b128
        if (g0 < NS) atomicMax(&s_idx[seg][g0], 2 * lane);
        if (g1 < NS) atomicMax(&s_idx[seg][g1], 2 * lane + 1);
    }
    __builtin_amdgcn_wave_barrier();

    // ---- phase C: max-scan K(j), gather (2x b64), interpolate, store ----
    #pragma unroll
    for (int r = 0; r < RPW; ++r) {
        const int seg = wave * RPW + r;
        const int2 xi = *reinterpret_cast<const int2*>(&s_idx[seg][2 * lane]);
        const int  m  = wave_iscan_max(max(xi.x, xi.y));
        const int  e  = dpp_i<0x138, 0xf>(m);   // prev pair's max; lane 0 -> 0
        const int  K0 = max(e, xi.x);           // interval of sample 2*lane
        const int  K1 = max(K0, xi.y);          // interval of sample 2*lane+1

        const float2* P = reinterpret_cast<const float2*>(&s_P[seg][0]);
        const float2 p0 = P[K0];                // (A, B): sample = A + u*B
        const float2 p1 = P[K1];
        float2 res;
        res.x = fmaf(u0, p0.y, p0.x);
        res.y = fmaf(u1, p1.y, p1.x);
        if (valid[r]) {
            const int ro = __builtin_amdgcn_readfirstlane(base + r);
            *reinterpret_cast<float2*>(out + (size_t)ro * NS + 2 * lane) = res;
        }
    }
}

extern "C" void kernel_launch(void* const* d_in, const int* in_sizes, int n_in,
                              void* d_out, int out_size, void* d_ws, size_t ws_size,
                              hipStream_t stream) {
    const float* bins    = (const float*)d_in[0];
    const float* weights = (const float*)d_in[1];
    float* out = (float*)d_out;

    const int n_rays = in_sizes[0] / NBINS;
    const int rays_per_block = WPB * RPW;
    const int blocks = (n_rays + rays_per_block - 1) / rays_per_block;
    sample_pdf_rank16<<<blocks, 64 * WPB, 0, stream>>>(bins, weights, out, n_rays);
}

// Round 18
// 63.012 us; speedup vs baseline: 1.1508x; 1.1508x over previous
//
#include <hip/hip_runtime.h>

// sample_pdf (NeRF, det=True) — rank-scan gather, 3 rays/wave, all-DPP lane
// ops, 128-thread blocks (r15 base). ONLY change vs r15: NON-TEMPORAL output
// stores (via clang ext_vector_type — __builtin_nontemporal_store rejects
// HIP_vector_type float2). Rationale: per-replay footprint = 265 MB inputs +
// 131 MB output = 396 MB churning a 256 MB L3 -> write allocations evict
// inputs between replays (measured read-hit ~50%: FETCH 132 MB vs 265 MB of
// reads). Output is write-once/never-read -> nt (no-allocate) store shrinks
// the cached footprint to ~L3 size, raising input hit rate and cutting the
// 900-cycle HBM-miss stalls that r11-r16's compute restructures couldn't hide.
//
// u_j=(2j+1)/256 fixed grid; g(c)=ceil(128c-0.5)=#{j:u_j<c} (exact in fp32).
// Interval k=[cdf[k],cdf[k+1]) owns sample slots [g_k,g_{k+1});
// K(j)=max{k: g_k<=j} == searchsorted(cdf,u_j,right)-1. Per ray:
// atomicMax-paint interval index k at start slot (only if g<NS), store params
// (A,B) with sample = A + u*B, wave max-scan forward-fills K(j), gather+fma.
//
// Lane 63: w0=w1=0 -> c0=c1=total*rcp(total) > 127.5/128 -> g=128 -> no paint.
//
// Cross-lane ops are DPP (pure VALU, HW-validated rounds 7-16):
//   scan: row_shr:1/2/4/8 + row_bcast:15 (rows 1,3) + row_bcast:31 (rows 2,3)
//   shfl_down(1)=wave_shl:1 (0x130); shfl_up(1)=wave_shr:1 (0x138, lane0->0)

#define M     126
#define NBINS 127
#define NS    128
#define RPW   3     // rays per wave
#define WPB   2     // waves per block (128 threads)

typedef float f32x2 __attribute__((ext_vector_type(2)));

template<int CTRL, int RM>
__device__ __forceinline__ float dpp_f(float x) {
    return __builtin_bit_cast(float,
        __builtin_amdgcn_update_dpp(0, __builtin_bit_cast(int, x),
                                    CTRL, RM, 0xf, true));
}
template<int CTRL, int RM>
__device__ __forceinline__ int dpp_i(int x) {
    return __builtin_amdgcn_update_dpp(0, x, CTRL, RM, 0xf, true);
}

__device__ __forceinline__ float wave_iscan_add(float x) {
    x += dpp_f<0x111, 0xf>(x);   // row_shr:1
    x += dpp_f<0x112, 0xf>(x);   // row_shr:2
    x += dpp_f<0x114, 0xf>(x);   // row_shr:4
    x += dpp_f<0x118, 0xf>(x);   // row_shr:8
    x += dpp_f<0x142, 0xa>(x);   // row_bcast:15 -> rows 1,3
    x += dpp_f<0x143, 0xc>(x);   // row_bcast:31 -> rows 2,3
    return x;
}
__device__ __forceinline__ int wave_iscan_max(int x) {
    x = max(x, dpp_i<0x111, 0xf>(x));
    x = max(x, dpp_i<0x112, 0xf>(x));
    x = max(x, dpp_i<0x114, 0xf>(x));
    x = max(x, dpp_i<0x118, 0xf>(x));
    x = max(x, dpp_i<0x142, 0xa>(x));
    x = max(x, dpp_i<0x143, 0xc>(x));
    return x;
}

__global__ __launch_bounds__(64 * WPB) void sample_pdf_rank18(
    const float* __restrict__ bins,
    const float* __restrict__ weights,
    float* __restrict__ out,
    int n_rays)
{
    __shared__ int    s_idx[WPB * RPW][NS];
    __shared__ float4 s_P[WPB * RPW][NS / 2];  // (A_even, B_even, A_odd, B_odd)

    const int wave = threadIdx.x >> 6;
    const int lane = threadIdx.x & 63;
    const int base = (blockIdx.x * WPB + wave) * RPW;

    const int  i0   = min(2 * lane, 126);      // branchless, OOB-safe
    const int  i1   = min(2 * lane + 1, 126);
    const int  iw   = min(2 * lane, 124);
    const bool full = (lane < 63);

    // ---- init paint slots ----
    #pragma unroll
    for (int r = 0; r < RPW; ++r)
        *reinterpret_cast<int2*>(&s_idx[wave * RPW + r][2 * lane]) = make_int2(0, 0);

    // ---- phase A: all global loads up front (scalar row bases) ----
    bool  valid[RPW];
    float b_a[RPW], b_b[RPW];
    float2 ww[RPW];
    #pragma unroll
    for (int r = 0; r < RPW; ++r) {
        const int ry = base + r;
        valid[r] = (ry < n_rays);
        const int ryu = __builtin_amdgcn_readfirstlane(valid[r] ? ry : n_rays - 1);
        const float* brow = bins    + (size_t)ryu * NBINS;   // SGPR base
        const float* wrow = weights + (size_t)ryu * M;
        b_a[r] = brow[i0];
        b_b[r] = brow[i1];
        ww[r]  = *reinterpret_cast<const float2*>(wrow + iw);
    }
    __builtin_amdgcn_wave_barrier();

    const float u0 = fmaf((float)lane, 0.015625f, 0.00390625f); // (4l+1)/256
    const float u1 = u0 + 0.0078125f;                           // (4l+3)/256

    // ---- phase B: scan -> cdf -> ranks -> params -> paint ----
    #pragma unroll
    for (int r = 0; r < RPW; ++r) {
        const float w0  = full ? ww[r].x + 1e-5f : 0.0f;   // lane63: exactly 0
        const float w1  = full ? ww[r].y + 1e-5f : 0.0f;
        const float rw0 = __builtin_amdgcn_rcpf(w0);       // off-chain
        const float rw1 = __builtin_amdgcn_rcpf(w1);
        const float b_c = dpp_f<0x130, 0xf>(b_a[r]);       // bins[2i+2]

        const float pair  = w0 + w1;
        const float ps    = wave_iscan_add(pair);          // inclusive prefix
        const float total = __shfl(ps, 63, 64);            // v_readlane
        const float inv   = __builtin_amdgcn_rcpf(total);
        const float excl  = ps - pair;
        const float c0 = excl * inv;                       // cdf[2i]
        const float c1 = (excl + w0) * inv;                // cdf[2i+1]
        const float c2 = ps * inv;                         // cdf[2i+2]

        const int g0 = (int)ceilf(fmaf(c0, 128.0f, -0.5f));  // exact rank
        const int g1 = (int)ceilf(fmaf(c1, 128.0f, -0.5f));

        const float dA = c1 - c0;
        const float dB = c2 - c1;
        const float fA = (dA < 1e-5f) ? 1.0f : total * rw0;
        const float fB = (dB < 1e-5f) ? 1.0f : total * rw1;
        const float slA = (b_b[r] - b_a[r]) * fA;
        const float slB = (b_c    - b_b[r]) * fB;
        const float A0  = fmaf(-c0, slA, b_a[r]);          // bl - cl*sl
        const float A1  = fmaf(-c1, slB, b_b[r]);

        const int seg = wave * RPW + r;
        s_P[seg][lane] = make_float4(A0, slA, A1, slB);    // one ds_write_b128
        if (g0 < NS) atomicMax(&s_idx[seg][g0], 2 * lane);
        if (g1 < NS) atomicMax(&s_idx[seg][g1], 2 * lane + 1);
    }
    __builtin_amdgcn_wave_barrier();

    // ---- phase C: max-scan K(j), gather (2x b64), interpolate, nt-store ----
    #pragma unroll
    for (int r = 0; r < RPW; ++r) {
        const int seg = wave * RPW + r;
        const int2 xi = *reinterpret_cast<const int2*>(&s_idx[seg][2 * lane]);
        const int  m  = wave_iscan_max(max(xi.x, xi.y));
        const int  e  = dpp_i<0x138, 0xf>(m);   // prev pair's max; lane 0 -> 0
        const int  K0 = max(e, xi.x);           // interval of sample 2*lane
        const int  K1 = max(K0, xi.y);          // interval of sample 2*lane+1

        const float2* P = reinterpret_cast<const float2*>(&s_P[seg][0]);
        const float2 p0 = P[K0];                // (A, B): sample = A + u*B
        const float2 p1 = P[K1];
        f32x2 res;
        res.x = fmaf(u0, p0.y, p0.x);
        res.y = fmaf(u1, p1.y, p1.x);
        if (valid[r]) {
            const int ro = __builtin_amdgcn_readfirstlane(base + r);
            // non-temporal (nt, no-allocate): output is write-once, never
            // re-read -> don't evict inputs from L2/L3 between replays.
            __builtin_nontemporal_store(
                res, reinterpret_cast<f32x2*>(out + (size_t)ro * NS + 2 * lane));
        }
    }
}

extern "C" void kernel_launch(void* const* d_in, const int* in_sizes, int n_in,
                              void* d_out, int out_size, void* d_ws, size_t ws_size,
                              hipStream_t stream) {
    const float* bins    = (const float*)d_in[0];
    const float* weights = (const float*)d_in[1];
    float* out = (float*)d_out;

    const int n_rays = in_sizes[0] / NBINS;
    const int rays_per_block = WPB * RPW;
    const int blocks = (n_rays + rays_per_block - 1) / rays_per_block;
    sample_pdf_rank18<<<blocks, 64 * WPB, 0, stream>>>(bins, weights, out, n_rays);
}